// Round 3
// baseline (402.661 us; speedup 1.0000x reference)
//
#include <hip/hip_runtime.h>
#include <hip/hip_bf16.h>

#define B_   4
#define T_   1024
#define DM   2048
#define QKVD 3072   // 64*(32+16)

typedef __attribute__((ext_vector_type(8))) short bf16x8;
typedef __attribute__((ext_vector_type(4))) short short4v;
typedef __attribute__((ext_vector_type(4))) float f32x4;

__device__ __forceinline__ void load_lds16(const void* g, void* l) {
  __builtin_amdgcn_global_load_lds((const __attribute__((address_space(1))) void*)g,
                                   (__attribute__((address_space(3))) void*)l, 16, 0, 0);
}

__device__ __forceinline__ short f2bf(float f) {
  __hip_bfloat16 h = __float2bfloat16(f);
  return *reinterpret_cast<short*>(&h);
}

__device__ __forceinline__ void store_elem(float* p, float v) { *p = v; }
__device__ __forceinline__ void store_elem(__hip_bfloat16* p, float v) { *p = __float2bfloat16(v); }

// Fused fp32 -> bf16 convert for x (8.4M), qkv_w (6.3M), out_w (4.2M).
__global__ __launch_bounds__(256) void cvt_kernel(const float* __restrict__ x,
                                                  const float* __restrict__ w1,
                                                  const float* __restrict__ w2,
                                                  short* __restrict__ xo,
                                                  short* __restrict__ w1o,
                                                  short* __restrict__ w2o) {
  unsigned c = blockIdx.x * 256u + threadIdx.x;  // 0 .. 4718591
  const float* src;
  short* dst;
  if (c < 2097152u) {                 // x: 8388608/4 chunks
    src = x; dst = xo;
  } else if (c < 3670016u) {          // qkv_w: 6291456/4 chunks
    c -= 2097152u; src = w1; dst = w1o;
  } else {                            // out_w: 4194304/4 chunks
    c -= 3670016u; src = w2; dst = w2o;
  }
  const float4 v = ((const float4*)src)[c];
  short4v o;
  o.x = f2bf(v.x); o.y = f2bf(v.y); o.z = f2bf(v.z); o.w = f2bf(v.w);
  ((short4v*)dst)[c] = o;
}

// C[M,N] = A[M,K] (bf16, row-major) * B[N,K]^T (bf16, row-major) + bias[N] (fp32)
// m97 structure: 128x128 tile, BK=32, 4 waves (2x2), 4x4 16x16x32 MFMA per wave.
template <typename CT>
__global__ __launch_bounds__(256) void gemm_bt(const short* __restrict__ A,
                                               const short* __restrict__ Bw,
                                               const float* __restrict__ bias,
                                               CT* __restrict__ C,
                                               int M, int N, int K) {
  __shared__ short As[128 * 32];
  __shared__ short Bs[128 * 32];
  const int tid  = threadIdx.x;
  const int lane = tid & 63;
  const int wave = tid >> 6;
  const int wm = wave >> 1, wn = wave & 1;
  const int r15 = lane & 15, quad = lane >> 4;
  const int m0 = blockIdx.y * 128, n0 = blockIdx.x * 128;

  f32x4 acc[4][4];
#pragma unroll
  for (int i = 0; i < 4; ++i)
#pragma unroll
    for (int j = 0; j < 4; ++j) acc[i][j] = {0.f, 0.f, 0.f, 0.f};

  // staging: 512 chunks of 16B per tile (128 rows x 4 chunks), 2 per thread.
  const int ca0 = tid, ca1 = tid + 256;
  const short* gA0 = A + (size_t)(m0 + (ca0 >> 2)) * K + (ca0 & 3) * 8;
  const short* gA1 = A + (size_t)(m0 + (ca1 >> 2)) * K + (ca1 & 3) * 8;
  const short* gB0 = Bw + (size_t)(n0 + (ca0 >> 2)) * K + (ca0 & 3) * 8;
  const short* gB1 = Bw + (size_t)(n0 + (ca1 >> 2)) * K + (ca1 & 3) * 8;
  short* lA0 = &As[ca0 * 8];
  short* lA1 = &As[ca1 * 8];
  short* lB0 = &Bs[ca0 * 8];
  short* lB1 = &Bs[ca1 * 8];

  for (int k0 = 0; k0 < K; k0 += 32) {
    __syncthreads();  // all waves done reading previous tile
    load_lds16(gA0, lA0);
    load_lds16(gA1, lA1);
    load_lds16(gB0, lB0);
    load_lds16(gB1, lB1);
    gA0 += 32; gA1 += 32; gB0 += 32; gB1 += 32;
    __syncthreads();  // vmcnt(0) drain before barrier -> LDS ready

    bf16x8 af[4], bfr[4];
#pragma unroll
    for (int tm = 0; tm < 4; ++tm)
      af[tm] = *(const bf16x8*)&As[(wm * 64 + tm * 16 + r15) * 32 + quad * 8];
#pragma unroll
    for (int tn = 0; tn < 4; ++tn)
      bfr[tn] = *(const bf16x8*)&Bs[(wn * 64 + tn * 16 + r15) * 32 + quad * 8];
#pragma unroll
    for (int tm = 0; tm < 4; ++tm)
#pragma unroll
      for (int tn = 0; tn < 4; ++tn)
        acc[tm][tn] = __builtin_amdgcn_mfma_f32_16x16x32_bf16(af[tm], bfr[tn], acc[tm][tn], 0, 0, 0);
  }

  // epilogue: C/D layout col=lane&15, row=quad*4+reg (verified m89/m91)
#pragma unroll
  for (int tn = 0; tn < 4; ++tn) {
    const int col = n0 + wn * 64 + tn * 16 + r15;
    const float bv = bias[col];
#pragma unroll
    for (int tm = 0; tm < 4; ++tm) {
      const int row = m0 + wm * 64 + tm * 16 + quad * 4;
#pragma unroll
      for (int v = 0; v < 4; ++v) {
        store_elem(&C[(size_t)(row + v) * N + col], acc[tm][tn][v] + bv);
      }
    }
  }
}

// In-place YaRN/NTK RoPE on q (with SM_SCALE folded in) and k, fp32 qkv buffer.
__global__ __launch_bounds__(256) void rope_kernel(float* __restrict__ qkv) {
  const int bt = blockIdx.x;      // (b,t) fused, 0..4095
  const int t = bt & (T_ - 1);
  float* row = qkv + (size_t)bt * QKVD;
#pragma unroll
  for (int it = 0; it < 5; ++it) {
    const int pid = it * 256 + threadIdx.x;  // 0..1279: 1024 q-pairs + 256 k-pairs
    float* base;
    int i;
    float scale;
    if (pid < 1024) {
      const int kv = pid >> 7, m = (pid >> 5) & 3;
      i = pid & 31;
      base = row + kv * 256 + m * 64;
      scale = 0.125f;  // SM_SCALE = 1/sqrt(64)
    } else {
      const int p = pid - 1024;
      const int kv = p >> 5;
      i = p & 31;
      base = row + 2048 + kv * 64;
      scale = 1.0f;
    }
    const float fi = (float)i;
    const float freq = __powf(150000.f, fi * (1.f / 32.f));
    float ramp = (fi - 4.3707300f) * (1.f / 9.3052397f);
    ramp = fminf(fmaxf(ramp, 0.f), 1.f);
    const float inv_freq = ramp / (32.f * freq) + (1.f - ramp) / freq;
    const float ph = (float)t * inv_freq;
    float c = __cosf(ph) * 1.3465736f;   // concentration = 0.1*ln(32)+1
    float s = __sinf(ph) * 1.3465736f;
    const float x1 = base[i], x2 = base[i + 32];
    base[i]      = (x1 * c - x2 * s) * scale;
    base[i + 32] = (x2 * c + x1 * s) * scale;
  }
}

// Sliding-window (128) causal attention with sinks. Block = (b, kv, 64 queries),
// wave = GQA head, lane = query. Fixed m=0 softmax (exact: softmax is
// shift-invariant and |s| is bounded well below exp overflow).
__global__ __launch_bounds__(256) void attn_kernel(const float* __restrict__ qkv,
                                                   const float* __restrict__ sinks,
                                                   __hip_bfloat16* __restrict__ attn_out) {
  __shared__ float Kt[64][64];
  __shared__ float Vt[64][64];
  const int lane = threadIdx.x & 63;
  const int m = threadIdx.x >> 6;    // GQA sub-head
  const int t0 = blockIdx.x * 64;
  const int kv = blockIdx.y;
  const int b = blockIdx.z;
  const int t = t0 + lane;

  const float* qrow = qkv + (size_t)(b * T_ + t) * QKVD + kv * 256 + m * 64;
  float4 q4[16];
#pragma unroll
  for (int dd = 0; dd < 16; ++dd) q4[dd] = *(const float4*)(qrow + dd * 4);

  float4 o4[16];
#pragma unroll
  for (int dd = 0; dd < 16; ++dd) o4[dd] = {0.f, 0.f, 0.f, 0.f};
  float l = 0.f;

  for (int tile = 0; tile < 3; ++tile) {
    const int j0 = t0 - 128 + tile * 64;
    if (j0 <= -64) continue;  // uniform across block: no keys in range
    __syncthreads();          // previous tile fully consumed
    // stage K,V tiles: 64 rows x 64 fp32 each; 1024 16B-chunks, 4 per thread
#pragma unroll
    for (int i = 0; i < 4; ++i) {
      const int c = i * 256 + threadIdx.x;
      const int r = c >> 4, cc = (c & 15) * 4;
      const float* grow = qkv + (size_t)(b * T_ + j0 + r) * QKVD + kv * 64;
      *(float4*)&Kt[r][cc] = *(const float4*)(grow + 2048 + cc);
      *(float4*)&Vt[r][cc] = *(const float4*)(grow + 2560 + cc);
    }
    __syncthreads();

    for (int r = 0; r < 64; ++r) {
      const int j = j0 + r;
      const float4* kr = (const float4*)&Kt[r][0];
      float s0 = 0.f, s1 = 0.f, s2 = 0.f, s3 = 0.f;
#pragma unroll
      for (int dd = 0; dd < 16; ++dd) {
        const float4 kk = kr[dd];
        s0 += q4[dd].x * kk.x;
        s1 += q4[dd].y * kk.y;
        s2 += q4[dd].z * kk.z;
        s3 += q4[dd].w * kk.w;
      }
      const float s = (s0 + s1) + (s2 + s3);
      const bool valid = (j <= t) && (j >= t - 127);
      const float e = valid ? __expf(s) : 0.f;
      l += e;
      const float4* vr = (const float4*)&Vt[r][0];
#pragma unroll
      for (int dd = 0; dd < 16; ++dd) {
        const float4 vv = vr[dd];
        o4[dd].x += e * vv.x;
        o4[dd].y += e * vv.y;
        o4[dd].z += e * vv.z;
        o4[dd].w += e * vv.w;
      }
    }
  }

  const int h = kv * 4 + m;
  const float denom = l + __expf(sinks[h]);
  const float inv = 1.f / denom;
  __hip_bfloat16* orow = attn_out + (size_t)(b * T_ + t) * DM + h * 64;
#pragma unroll
  for (int dd = 0; dd < 16; ++dd) {
    orow[dd * 4 + 0] = __float2bfloat16(o4[dd].x * inv);
    orow[dd * 4 + 1] = __float2bfloat16(o4[dd].y * inv);
    orow[dd * 4 + 2] = __float2bfloat16(o4[dd].z * inv);
    orow[dd * 4 + 3] = __float2bfloat16(o4[dd].w * inv);
  }
}

extern "C" void kernel_launch(void* const* d_in, const int* in_sizes, int n_in,
                              void* d_out, int out_size, void* d_ws, size_t ws_size,
                              hipStream_t stream) {
  const float* x      = (const float*)d_in[0];   // fp32 (B,T,DM)
  const float* qkv_w  = (const float*)d_in[1];   // fp32 (3072,2048)
  const float* qkv_b  = (const float*)d_in[2];   // fp32 (3072,)
  const float* out_w  = (const float*)d_in[3];   // fp32 (2048,2048)
  const float* out_b  = (const float*)d_in[4];   // fp32 (2048,)
  const float* sinks  = (const float*)d_in[5];   // fp32 (32,)

  // ws layout (84 MiB):
  //   [0, 50331648)            qkv fp32 (4096 x 3072)
  //   [50331648, 67108864)     x_bf16 (16.8 MB), later reused as attn bf16 out
  //   [67108864, 79691776)     qkv_w bf16
  //   [79691776, 88080384)     out_w bf16
  char* ws = (char*)d_ws;
  float* qkv = (float*)ws;
  short* xb  = (short*)(ws + 50331648);
  short* wqb = (short*)(ws + 67108864);
  short* wob = (short*)(ws + 79691776);
  __hip_bfloat16* attn = (__hip_bfloat16*)xb;  // aliased: xb dead after gemm1
  float* out = (float*)d_out;                  // reference output dtype = fp32

  // 0) fp32 -> bf16 convert of x, qkv_w, out_w
  cvt_kernel<<<18432, 256, 0, stream>>>(x, qkv_w, out_w, xb, wqb, wob);
  // 1) fused QKV projection: qkv = x @ qkv_w^T + qkv_b  (fp32 out)
  gemm_bt<float><<<dim3(QKVD / 128, 4096 / 128), 256, 0, stream>>>(
      xb, wqb, qkv_b, qkv, 4096, QKVD, 2048);
  // 2) RoPE in place on q (scaled) and k
  rope_kernel<<<4096, 256, 0, stream>>>(qkv);
  // 3) sliding-window attention with sinks -> bf16 (B,T,2048)
  attn_kernel<<<dim3(T_ / 64, 8, B_), 256, 0, stream>>>(qkv, sinks, attn);
  // 4) output projection: out = attn @ out_w^T + out_b  (fp32 out)
  gemm_bt<float><<<dim3(DM / 128, 4096 / 128), 256, 0, stream>>>(
      (const short*)attn, wob, out_b, out, 4096, DM, 2048);
}

// Round 4
// 279.047 us; speedup vs baseline: 1.4430x; 1.4430x over previous
//
#include <hip/hip_runtime.h>
#include <hip/hip_bf16.h>

#define B_   4
#define T_   1024
#define DM   2048
#define QKVD 3072   // 64*(32+16)

typedef __attribute__((ext_vector_type(8))) short bf16x8;
typedef __attribute__((ext_vector_type(4))) short short4v;
typedef __attribute__((ext_vector_type(4))) float f32x4;

__device__ __forceinline__ void load_lds16(const void* g, void* l) {
  __builtin_amdgcn_global_load_lds((const __attribute__((address_space(1))) void*)g,
                                   (__attribute__((address_space(3))) void*)l, 16, 0, 0);
}

__device__ __forceinline__ short f2bf(float f) {
  __hip_bfloat16 h = __float2bfloat16(f);
  return *reinterpret_cast<short*>(&h);
}

__device__ __forceinline__ void store_elem(float* p, float v) { *p = v; }
__device__ __forceinline__ void store_elem(__hip_bfloat16* p, float v) { *p = __float2bfloat16(v); }

// Fused fp32 -> bf16 convert for x (8.4M), qkv_w (6.3M), out_w (4.2M).
__global__ __launch_bounds__(256) void cvt_kernel(const float* __restrict__ x,
                                                  const float* __restrict__ w1,
                                                  const float* __restrict__ w2,
                                                  short* __restrict__ xo,
                                                  short* __restrict__ w1o,
                                                  short* __restrict__ w2o) {
  unsigned c = blockIdx.x * 256u + threadIdx.x;  // 0 .. 4718591
  const float* src;
  short* dst;
  if (c < 2097152u) {                 // x: 8388608/4 chunks
    src = x; dst = xo;
  } else if (c < 3670016u) {          // qkv_w: 6291456/4 chunks
    c -= 2097152u; src = w1; dst = w1o;
  } else {                            // out_w: 4194304/4 chunks
    c -= 3670016u; src = w2; dst = w2o;
  }
  const float4 v = ((const float4*)src)[c];
  short4v o;
  o.x = f2bf(v.x); o.y = f2bf(v.y); o.z = f2bf(v.z); o.w = f2bf(v.w);
  ((short4v*)dst)[c] = o;
}

// C[M,N] = A[M,K] (bf16, row-major) * B[N,K]^T (bf16, row-major) + bias[N] (fp32)
// m97 structure: 128x128 tile, BK=32, 4 waves (2x2), 4x4 16x16x32 MFMA per wave.
template <typename CT>
__global__ __launch_bounds__(256) void gemm_bt(const short* __restrict__ A,
                                               const short* __restrict__ Bw,
                                               const float* __restrict__ bias,
                                               CT* __restrict__ C,
                                               int M, int N, int K) {
  __shared__ short As[128 * 32];
  __shared__ short Bs[128 * 32];
  const int tid  = threadIdx.x;
  const int lane = tid & 63;
  const int wave = tid >> 6;
  const int wm = wave >> 1, wn = wave & 1;
  const int r15 = lane & 15, quad = lane >> 4;
  const int m0 = blockIdx.y * 128, n0 = blockIdx.x * 128;

  f32x4 acc[4][4];
#pragma unroll
  for (int i = 0; i < 4; ++i)
#pragma unroll
    for (int j = 0; j < 4; ++j) acc[i][j] = {0.f, 0.f, 0.f, 0.f};

  const int ca0 = tid, ca1 = tid + 256;
  const short* gA0 = A + (size_t)(m0 + (ca0 >> 2)) * K + (ca0 & 3) * 8;
  const short* gA1 = A + (size_t)(m0 + (ca1 >> 2)) * K + (ca1 & 3) * 8;
  const short* gB0 = Bw + (size_t)(n0 + (ca0 >> 2)) * K + (ca0 & 3) * 8;
  const short* gB1 = Bw + (size_t)(n0 + (ca1 >> 2)) * K + (ca1 & 3) * 8;
  short* lA0 = &As[ca0 * 8];
  short* lA1 = &As[ca1 * 8];
  short* lB0 = &Bs[ca0 * 8];
  short* lB1 = &Bs[ca1 * 8];

  for (int k0 = 0; k0 < K; k0 += 32) {
    __syncthreads();
    load_lds16(gA0, lA0);
    load_lds16(gA1, lA1);
    load_lds16(gB0, lB0);
    load_lds16(gB1, lB1);
    gA0 += 32; gA1 += 32; gB0 += 32; gB1 += 32;
    __syncthreads();

    bf16x8 af[4], bfr[4];
#pragma unroll
    for (int tm = 0; tm < 4; ++tm)
      af[tm] = *(const bf16x8*)&As[(wm * 64 + tm * 16 + r15) * 32 + quad * 8];
#pragma unroll
    for (int tn = 0; tn < 4; ++tn)
      bfr[tn] = *(const bf16x8*)&Bs[(wn * 64 + tn * 16 + r15) * 32 + quad * 8];
#pragma unroll
    for (int tm = 0; tm < 4; ++tm)
#pragma unroll
      for (int tn = 0; tn < 4; ++tn)
        acc[tm][tn] = __builtin_amdgcn_mfma_f32_16x16x32_bf16(af[tm], bfr[tn], acc[tm][tn], 0, 0, 0);
  }

#pragma unroll
  for (int tn = 0; tn < 4; ++tn) {
    const int col = n0 + wn * 64 + tn * 16 + r15;
    const float bv = bias[col];
#pragma unroll
    for (int tm = 0; tm < 4; ++tm) {
      const int row = m0 + wm * 64 + tm * 16 + quad * 4;
#pragma unroll
      for (int v = 0; v < 4; ++v) {
        store_elem(&C[(size_t)(row + v) * N + col], acc[tm][tn][v] + bv);
      }
    }
  }
}

// In-place YaRN/NTK RoPE on q (with SM_SCALE folded in) and k, fp32 qkv buffer.
__global__ __launch_bounds__(256) void rope_kernel(float* __restrict__ qkv) {
  const int bt = blockIdx.x;      // (b,t) fused, 0..4095
  const int t = bt & (T_ - 1);
  float* row = qkv + (size_t)bt * QKVD;
#pragma unroll
  for (int it = 0; it < 5; ++it) {
    const int pid = it * 256 + threadIdx.x;  // 0..1279: 1024 q-pairs + 256 k-pairs
    float* base;
    int i;
    float scale;
    if (pid < 1024) {
      const int kv = pid >> 7, m = (pid >> 5) & 3;
      i = pid & 31;
      base = row + kv * 256 + m * 64;
      scale = 0.125f;  // SM_SCALE = 1/sqrt(64)
    } else {
      const int p = pid - 1024;
      const int kv = p >> 5;
      i = p & 31;
      base = row + 2048 + kv * 64;
      scale = 1.0f;
    }
    const float fi = (float)i;
    const float freq = __powf(150000.f, fi * (1.f / 32.f));
    float ramp = (fi - 4.3707300f) * (1.f / 9.3052397f);
    ramp = fminf(fmaxf(ramp, 0.f), 1.f);
    const float inv_freq = ramp / (32.f * freq) + (1.f - ramp) / freq;
    const float ph = (float)t * inv_freq;
    float c = __cosf(ph) * 1.3465736f;   // concentration = 0.1*ln(32)+1
    float s = __sinf(ph) * 1.3465736f;
    const float x1 = base[i], x2 = base[i + 32];
    base[i]      = (x1 * c - x2 * s) * scale;
    base[i + 32] = (x2 * c + x1 * s) * scale;
  }
}

// MFMA flash-style sliding-window attention with sinks.
// Block = (b, kv, 64-query tile), 4 waves, wave = GQA sub-head m.
// S = Q K^T via 16x16x32 bf16 MFMA (Q in A-frags from registers, K bf16 in LDS
// as B-frags); mask+exp in C/D layout; P -> per-wave LDS -> A-frags; V staged
// transposed (Vt[dim][key]) so PV B-frags are contiguous ds_read_b128.
// Fixed m=0 softmax (exact: shift-invariant, scores bounded ~N(0,1.5)).
// LDS rows padded to stride 72 (16B-aligned for b128, breaks 32-bank stride).
#define LSTR 72
__global__ __launch_bounds__(256, 2) void attn_kernel(const float* __restrict__ qkv,
                                                      const float* __restrict__ sinks,
                                                      __hip_bfloat16* __restrict__ attn_out) {
  __shared__ short Kb[64 * LSTR];      // [key][dim]
  __shared__ short Vt[64 * LSTR];      // [dim][key] (transposed)
  __shared__ short Pl[4][64 * LSTR];   // per-wave [query][key]
  const int tid  = threadIdx.x;
  const int lane = tid & 63;
  const int m    = tid >> 6;          // GQA sub-head
  const int r15  = lane & 15, quad = lane >> 4;
  const int t0 = blockIdx.x * 64;
  const int kv = blockIdx.y;
  const int b  = blockIdx.z;

  // Q A-fragments: row = tm*16 + r15 (query), k = kc*32 + quad*8 + j (dim)
  bf16x8 qf[4][2];
#pragma unroll
  for (int tm = 0; tm < 4; ++tm)
#pragma unroll
    for (int kc = 0; kc < 2; ++kc) {
      const float* qp = qkv + (size_t)(b * T_ + t0 + tm * 16 + r15) * QKVD
                      + kv * 256 + m * 64 + kc * 32 + quad * 8;
      const float4 a0 = *(const float4*)qp;
      const float4 a1 = *(const float4*)(qp + 4);
      bf16x8 f;
      f[0] = f2bf(a0.x); f[1] = f2bf(a0.y); f[2] = f2bf(a0.z); f[3] = f2bf(a0.w);
      f[4] = f2bf(a1.x); f[5] = f2bf(a1.y); f[6] = f2bf(a1.z); f[7] = f2bf(a1.w);
      qf[tm][kc] = f;
    }

  f32x4 oacc[4][4];
#pragma unroll
  for (int i = 0; i < 4; ++i)
#pragma unroll
    for (int j = 0; j < 4; ++j) oacc[i][j] = {0.f, 0.f, 0.f, 0.f};
  float lf[16];
#pragma unroll
  for (int i = 0; i < 16; ++i) lf[i] = 0.f;

  const int sr = tid >> 2, sg = tid & 3;  // staging: row 0..63, dim-group 0..3

  for (int tile = 0; tile < 3; ++tile) {
    const int j0 = t0 - 128 + tile * 64;
    if (j0 < 0) continue;  // block-uniform
    __syncthreads();       // previous tile fully consumed
    {
      const float* kp = qkv + (size_t)(b * T_ + j0 + sr) * QKVD + 2048 + kv * 64 + sg * 16;
      const float* vp = kp + 512;
#pragma unroll
      for (int i = 0; i < 4; ++i) {
        const float4 kk = ((const float4*)kp)[i];
        short4v ks;
        ks.x = f2bf(kk.x); ks.y = f2bf(kk.y); ks.z = f2bf(kk.z); ks.w = f2bf(kk.w);
        *(short4v*)&Kb[sr * LSTR + sg * 16 + i * 4] = ks;
        const float4 vv = ((const float4*)vp)[i];
        Vt[(sg * 16 + i * 4 + 0) * LSTR + sr] = f2bf(vv.x);
        Vt[(sg * 16 + i * 4 + 1) * LSTR + sr] = f2bf(vv.y);
        Vt[(sg * 16 + i * 4 + 2) * LSTR + sr] = f2bf(vv.z);
        Vt[(sg * 16 + i * 4 + 3) * LSTR + sr] = f2bf(vv.w);
      }
    }
    __syncthreads();

    // S = Q K^T : C/D layout col(key)=tn*16+r15, row(query)=tm*16+quad*4+reg
    f32x4 sacc[4][4];
#pragma unroll
    for (int i = 0; i < 4; ++i)
#pragma unroll
      for (int j = 0; j < 4; ++j) sacc[i][j] = {0.f, 0.f, 0.f, 0.f};
#pragma unroll
    for (int kc = 0; kc < 2; ++kc) {
      bf16x8 bk[4];
#pragma unroll
      for (int tn = 0; tn < 4; ++tn)
        bk[tn] = *(const bf16x8*)&Kb[(tn * 16 + r15) * LSTR + kc * 32 + quad * 8];
#pragma unroll
      for (int tm = 0; tm < 4; ++tm)
#pragma unroll
        for (int tn = 0; tn < 4; ++tn)
          sacc[tm][tn] = __builtin_amdgcn_mfma_f32_16x16x32_bf16(qf[tm][kc], bk[tn], sacc[tm][tn], 0, 0, 0);
    }

    // mask + exp + row-sum partials + write P to per-wave LDS (no barrier needed)
    short* pl = &Pl[m][0];
#pragma unroll
    for (int tm = 0; tm < 4; ++tm)
#pragma unroll
      for (int v = 0; v < 4; ++v) {
        const int q = tm * 16 + quad * 4 + v;
        const int t = t0 + q;
        float lsum = 0.f;
#pragma unroll
        for (int tn = 0; tn < 4; ++tn) {
          const int j = j0 + tn * 16 + r15;
          const bool valid = (unsigned)(t - j) <= 127u;  // j<=t && j>=t-127
          const float e = valid ? __expf(sacc[tm][tn][v]) : 0.f;
          lsum += e;
          pl[q * LSTR + tn * 16 + r15] = f2bf(e);
        }
        lf[tm * 4 + v] += lsum;
      }

    // O += P V : A-frags from Pl (row=query=tm*16+r15, k=key), B-frags from Vt
    // (row=dim=tn*16+r15, k=key). Same-wave LDS RAW handled by lgkmcnt.
#pragma unroll
    for (int kc = 0; kc < 2; ++kc) {
      bf16x8 ap[4], bv[4];
#pragma unroll
      for (int tm = 0; tm < 4; ++tm)
        ap[tm] = *(const bf16x8*)&pl[(tm * 16 + r15) * LSTR + kc * 32 + quad * 8];
#pragma unroll
      for (int tn = 0; tn < 4; ++tn)
        bv[tn] = *(const bf16x8*)&Vt[(tn * 16 + r15) * LSTR + kc * 32 + quad * 8];
#pragma unroll
      for (int tm = 0; tm < 4; ++tm)
#pragma unroll
        for (int tn = 0; tn < 4; ++tn)
          oacc[tm][tn] = __builtin_amdgcn_mfma_f32_16x16x32_bf16(ap[tm], bv[tn], oacc[tm][tn], 0, 0, 0);
    }
  }

  // row-sum reduce across the 16-lane r15 group (same quad), add sink, store
#pragma unroll
  for (int i = 0; i < 16; ++i) {
    float v = lf[i];
    v += __shfl_xor(v, 1, 64);
    v += __shfl_xor(v, 2, 64);
    v += __shfl_xor(v, 4, 64);
    v += __shfl_xor(v, 8, 64);
    lf[i] = v;
  }
  const int h = kv * 4 + m;
  const float snk = __expf(sinks[h]);
#pragma unroll
  for (int tm = 0; tm < 4; ++tm)
#pragma unroll
    for (int v = 0; v < 4; ++v) {
      const float inv = 1.f / (lf[tm * 4 + v] + snk);
      const int q = tm * 16 + quad * 4 + v;
      __hip_bfloat16* op = attn_out + (size_t)(b * T_ + t0 + q) * DM + h * 64;
#pragma unroll
      for (int tn = 0; tn < 4; ++tn)
        op[tn * 16 + r15] = __float2bfloat16(oacc[tm][tn][v] * inv);
    }
}

extern "C" void kernel_launch(void* const* d_in, const int* in_sizes, int n_in,
                              void* d_out, int out_size, void* d_ws, size_t ws_size,
                              hipStream_t stream) {
  const float* x      = (const float*)d_in[0];   // fp32 (B,T,DM)
  const float* qkv_w  = (const float*)d_in[1];   // fp32 (3072,2048)
  const float* qkv_b  = (const float*)d_in[2];   // fp32 (3072,)
  const float* out_w  = (const float*)d_in[3];   // fp32 (2048,2048)
  const float* out_b  = (const float*)d_in[4];   // fp32 (2048,)
  const float* sinks  = (const float*)d_in[5];   // fp32 (32,)

  char* ws = (char*)d_ws;
  float* qkv = (float*)ws;                       // 50.3 MB fp32 qkv
  short* xb  = (short*)(ws + 50331648);          // x bf16, later attn bf16 out
  short* wqb = (short*)(ws + 67108864);          // qkv_w bf16
  short* wob = (short*)(ws + 79691776);          // out_w bf16
  __hip_bfloat16* attn = (__hip_bfloat16*)xb;    // aliased: xb dead after gemm1
  float* out = (float*)d_out;                    // reference output dtype = fp32

  cvt_kernel<<<18432, 256, 0, stream>>>(x, qkv_w, out_w, xb, wqb, wob);
  gemm_bt<float><<<dim3(QKVD / 128, 4096 / 128), 256, 0, stream>>>(
      xb, wqb, qkv_b, qkv, 4096, QKVD, 2048);
  rope_kernel<<<4096, 256, 0, stream>>>(qkv);
  attn_kernel<<<dim3(T_ / 64, 8, B_), 256, 0, stream>>>(qkv, sinks, attn);
  gemm_bt<float><<<dim3(DM / 128, 4096 / 128), 256, 0, stream>>>(
      (const short*)attn, wob, out_b, out, 4096, DM, 2048);
}

// Round 5
// 264.422 us; speedup vs baseline: 1.5228x; 1.0553x over previous
//
#include <hip/hip_runtime.h>
#include <hip/hip_bf16.h>

#define B_   4
#define T_   1024
#define DM   2048
#define QKVD 3072   // 64*(32+16)

typedef __attribute__((ext_vector_type(8))) short bf16x8;
typedef __attribute__((ext_vector_type(4))) short short4v;
typedef __attribute__((ext_vector_type(4))) float f32x4;

__device__ __forceinline__ void load_lds16(const void* g, void* l) {
  __builtin_amdgcn_global_load_lds((const __attribute__((address_space(1))) void*)g,
                                   (__attribute__((address_space(3))) void*)l, 16, 0, 0);
}

__device__ __forceinline__ short f2bf(float f) {
  __hip_bfloat16 h = __float2bfloat16(f);
  return *reinterpret_cast<short*>(&h);
}

// Fused fp32 -> bf16 convert for x (8.4M), qkv_w (6.3M), out_w (4.2M).
__global__ __launch_bounds__(256) void cvt_kernel(const float* __restrict__ x,
                                                  const float* __restrict__ w1,
                                                  const float* __restrict__ w2,
                                                  short* __restrict__ xo,
                                                  short* __restrict__ w1o,
                                                  short* __restrict__ w2o) {
  unsigned c = blockIdx.x * 256u + threadIdx.x;  // 0 .. 4718591
  const float* src;
  short* dst;
  if (c < 2097152u) {                 // x
    src = x; dst = xo;
  } else if (c < 3670016u) {          // qkv_w
    c -= 2097152u; src = w1; dst = w1o;
  } else {                            // out_w
    c -= 3670016u; src = w2; dst = w2o;
  }
  const float4 v = ((const float4*)src)[c];
  short4v o;
  o.x = f2bf(v.x); o.y = f2bf(v.y); o.z = f2bf(v.z); o.w = f2bf(v.w);
  ((short4v*)dst)[c] = o;
}

// Shared GEMM K-loop (m97 structure + XOR bank swizzle).
// LDS chunk (row r, q') holds global chunk q' ^ ((r>>1)&3): frag b128 reads
// then spread 16 r15-lanes over 8 bank-groups 2-way (free, m136) instead of
// the unswizzled 4-way+ aliasing (6.29M conflict cycles measured round 4).
#define GEMM_PROLOGUE_AND_KLOOP(A_, B_ptr, K_)                                     \
  __shared__ short As[128 * 32];                                                   \
  __shared__ short Bs[128 * 32];                                                   \
  const int tid  = threadIdx.x;                                                    \
  const int lane = tid & 63;                                                       \
  const int wave = tid >> 6;                                                       \
  const int wm = wave >> 1, wn = wave & 1;                                         \
  const int r15 = lane & 15, quad = lane >> 4;                                     \
  const int m0 = blockIdx.y * 128, n0 = blockIdx.x * 128;                          \
  f32x4 acc[4][4];                                                                 \
  _Pragma("unroll") for (int i = 0; i < 4; ++i)                                    \
    _Pragma("unroll") for (int j = 0; j < 4; ++j) acc[i][j] = {0.f, 0.f, 0.f, 0.f};\
  const int ca0 = tid, ca1 = tid + 256;                                            \
  const int sr0 = ca0 >> 2, sr1 = ca1 >> 2;                                        \
  const int sq0 = (ca0 & 3) ^ ((sr0 >> 1) & 3);                                    \
  const int sq1 = (ca1 & 3) ^ ((sr1 >> 1) & 3);                                    \
  const short* gA0 = A_ + (size_t)(m0 + sr0) * K_ + sq0 * 8;                       \
  const short* gA1 = A_ + (size_t)(m0 + sr1) * K_ + sq1 * 8;                       \
  const short* gB0 = B_ptr + (size_t)(n0 + sr0) * K_ + sq0 * 8;                    \
  const short* gB1 = B_ptr + (size_t)(n0 + sr1) * K_ + sq1 * 8;                    \
  short* lA0 = &As[ca0 * 8];                                                       \
  short* lA1 = &As[ca1 * 8];                                                       \
  short* lB0 = &Bs[ca0 * 8];                                                       \
  short* lB1 = &Bs[ca1 * 8];                                                       \
  const int sw = (r15 >> 1) & 3;                                                   \
  const int fo = (quad ^ sw) * 8;                                                  \
  for (int k0 = 0; k0 < K_; k0 += 32) {                                            \
    __syncthreads();                                                               \
    load_lds16(gA0, lA0);                                                          \
    load_lds16(gA1, lA1);                                                          \
    load_lds16(gB0, lB0);                                                          \
    load_lds16(gB1, lB1);                                                          \
    gA0 += 32; gA1 += 32; gB0 += 32; gB1 += 32;                                    \
    __syncthreads();                                                               \
    bf16x8 af[4], bfr[4];                                                          \
    _Pragma("unroll") for (int tm = 0; tm < 4; ++tm)                               \
      af[tm] = *(const bf16x8*)&As[(wm * 64 + tm * 16 + r15) * 32 + fo];           \
    _Pragma("unroll") for (int tn = 0; tn < 4; ++tn)                               \
      bfr[tn] = *(const bf16x8*)&Bs[(wn * 64 + tn * 16 + r15) * 32 + fo];          \
    _Pragma("unroll") for (int tm = 0; tm < 4; ++tm)                               \
      _Pragma("unroll") for (int tn = 0; tn < 4; ++tn)                             \
        acc[tm][tn] = __builtin_amdgcn_mfma_f32_16x16x32_bf16(af[tm], bfr[tn],     \
                                                              acc[tm][tn], 0, 0, 0);\
  }

// QKV projection with fused bias + YaRN RoPE + SM_SCALE; q/k -> bf16 qkvb,
// v -> bf16 vT[b][kv][d][t] (transposed for attention's PV B-frags).
__global__ __launch_bounds__(256) void gemm_qkv(const short* __restrict__ A,
                                                const short* __restrict__ Bw,
                                                const float* __restrict__ bias,
                                                short* __restrict__ qkvb,
                                                short* __restrict__ vT) {
  GEMM_PROLOGUE_AND_KLOOP(A, Bw, 2048)

  if (blockIdx.x < 20) {
    // q (cols<2048) or k (2048..2559): bias + rope (+0.125 scale for q)
    const float scale = (blockIdx.x < 16) ? 0.125f : 1.0f;
    float invf[2];
#pragma unroll
    for (int tnh = 0; tnh < 2; ++tnh) {
      const float fi = (float)(tnh * 16 + r15);   // i = col & 31
      const float freq = __powf(150000.f, fi * (1.f / 32.f));
      float ramp = (fi - 4.3707300f) * (1.f / 9.3052397f);
      ramp = fminf(fmaxf(ramp, 0.f), 1.f);
      invf[tnh] = ramp / (32.f * freq) + (1.f - ramp) / freq;
    }
    float bv[4];
#pragma unroll
    for (int tn = 0; tn < 4; ++tn) bv[tn] = bias[n0 + wn * 64 + tn * 16 + r15];
#pragma unroll
    for (int tm = 0; tm < 4; ++tm)
#pragma unroll
      for (int v = 0; v < 4; ++v) {
        const int row = m0 + wm * 64 + tm * 16 + quad * 4 + v;
        const float ft = (float)(row & 1023);       // per-batch position
#pragma unroll
        for (int tnh = 0; tnh < 2; ++tnh) {
          const float ph = ft * invf[tnh];
          const float c = __cosf(ph) * 1.3465736f;  // concentration = 0.1*ln(32)+1
          const float s = __sinf(ph) * 1.3465736f;
          const float x1 = acc[tm][tnh][v] + bv[tnh];
          const float x2 = acc[tm][tnh + 2][v] + bv[tnh + 2];
          short* qp = qkvb + (size_t)row * QKVD + (n0 + wn * 64 + tnh * 16 + r15);
          qp[0]  = f2bf((x1 * c - x2 * s) * scale);
          qp[32] = f2bf((x2 * c + x1 * s) * scale);
        }
      }
  } else {
    // v (cols 2560..3071): bias, write transposed vT[b][kv][d][t], short4 packs
#pragma unroll
    for (int tn = 0; tn < 4; ++tn) {
      const int col = n0 + wn * 64 + tn * 16 + r15;
      const float bvv = bias[col];
      const int d = col & 63;
      const int kvh = (col - 2560) >> 6;
#pragma unroll
      for (int tm = 0; tm < 4; ++tm) {
        const int row = m0 + wm * 64 + tm * 16 + quad * 4;
        const int bb = row >> 10, tt = row & 1023;
        short4v st;
        st.x = f2bf(acc[tm][tn][0] + bvv);
        st.y = f2bf(acc[tm][tn][1] + bvv);
        st.z = f2bf(acc[tm][tn][2] + bvv);
        st.w = f2bf(acc[tm][tn][3] + bvv);
        *(short4v*)&vT[(size_t)((bb * 8 + kvh) * 64 + d) * 1024 + tt] = st;
      }
    }
  }
}

// Output projection: C fp32 = A bf16 * B^T bf16 + bias
__global__ __launch_bounds__(256) void gemm_out(const short* __restrict__ A,
                                                const short* __restrict__ Bw,
                                                const float* __restrict__ bias,
                                                float* __restrict__ C) {
  GEMM_PROLOGUE_AND_KLOOP(A, Bw, 2048)
#pragma unroll
  for (int tn = 0; tn < 4; ++tn) {
    const int col = n0 + wn * 64 + tn * 16 + r15;
    const float bv = bias[col];
#pragma unroll
    for (int tm = 0; tm < 4; ++tm) {
      const int row = m0 + wm * 64 + tm * 16 + quad * 4;
#pragma unroll
      for (int v = 0; v < 4; ++v)
        C[(size_t)(row + v) * DM + col] = acc[tm][tn][v] + bv;
    }
  }
}

// MFMA flash-style sliding-window attention, all-bf16 inputs.
// Block = (b, kv, 32-query tile), 4 waves = 4 GQA sub-heads, 4 blocks/CU.
// K from qkvb rows, V from vT (pre-transposed) -> straight b128 staging into
// LDS padded to stride 72 (measured 0 conflicts round 4). Fixed m=0 softmax.
#define LSTR 72
__global__ __launch_bounds__(256, 4) void attn_kernel(const short* __restrict__ qkvb,
                                                      const short* __restrict__ vT,
                                                      const float* __restrict__ sinks,
                                                      short* __restrict__ attn_out) {
  __shared__ short Kb[64 * LSTR];      // [key][dim]
  __shared__ short Vt[64 * LSTR];      // [dim][key]
  __shared__ short Pl[4][32 * LSTR];   // per-wave [query][key]
  const int tid  = threadIdx.x;
  const int lane = tid & 63;
  const int m    = tid >> 6;
  const int r15  = lane & 15, quad = lane >> 4;
  const int t0 = blockIdx.x * 32;
  const int kv = blockIdx.y;
  const int b  = blockIdx.z;

  bf16x8 qf[2][2];
#pragma unroll
  for (int tm = 0; tm < 2; ++tm)
#pragma unroll
    for (int kc = 0; kc < 2; ++kc)
      qf[tm][kc] = *(const bf16x8*)&qkvb[(size_t)(b * T_ + t0 + tm * 16 + r15) * QKVD
                                         + kv * 256 + m * 64 + kc * 32 + quad * 8];

  f32x4 oacc[2][4];
#pragma unroll
  for (int i = 0; i < 2; ++i)
#pragma unroll
    for (int j = 0; j < 4; ++j) oacc[i][j] = {0.f, 0.f, 0.f, 0.f};
  float lf[8];
#pragma unroll
  for (int i = 0; i < 8; ++i) lf[i] = 0.f;

  // 64-aligned key tiles covering [max(0, t0-127), t0+31]
  const int jt_lo = (t0 >= 127) ? ((t0 - 127) >> 6) : 0;
  const int jt_hi = (t0 + 31) >> 6;

  for (int jt = jt_lo; jt <= jt_hi; ++jt) {
    const int j0 = jt * 64;
    __syncthreads();  // previous tile fully consumed
#pragma unroll
    for (int i = 0; i < 2; ++i) {
      const int c = i * 256 + tid;
      const int r = c >> 3, qc = c & 7;
      const bf16x8 kk = *(const bf16x8*)&qkvb[(size_t)(b * T_ + j0 + r) * QKVD
                                              + 2048 + kv * 64 + qc * 8];
      *(bf16x8*)&Kb[r * LSTR + qc * 8] = kk;
      const bf16x8 vv = *(const bf16x8*)&vT[(size_t)((b * 8 + kv) * 64 + r) * 1024
                                            + j0 + qc * 8];
      *(bf16x8*)&Vt[r * LSTR + qc * 8] = vv;
    }
    __syncthreads();

    // S = Q K^T : C/D layout col(key)=tn*16+r15, row(query)=tm*16+quad*4+v
    f32x4 sacc[2][4];
#pragma unroll
    for (int i = 0; i < 2; ++i)
#pragma unroll
      for (int j = 0; j < 4; ++j) sacc[i][j] = {0.f, 0.f, 0.f, 0.f};
#pragma unroll
    for (int kc = 0; kc < 2; ++kc) {
      bf16x8 bk[4];
#pragma unroll
      for (int tn = 0; tn < 4; ++tn)
        bk[tn] = *(const bf16x8*)&Kb[(tn * 16 + r15) * LSTR + kc * 32 + quad * 8];
#pragma unroll
      for (int tm = 0; tm < 2; ++tm)
#pragma unroll
        for (int tn = 0; tn < 4; ++tn)
          sacc[tm][tn] = __builtin_amdgcn_mfma_f32_16x16x32_bf16(qf[tm][kc], bk[tn],
                                                                 sacc[tm][tn], 0, 0, 0);
    }

    // mask + exp + row-sum partials + P to per-wave LDS
    short* pl = &Pl[m][0];
#pragma unroll
    for (int tm = 0; tm < 2; ++tm)
#pragma unroll
      for (int v = 0; v < 4; ++v) {
        const int ql = tm * 16 + quad * 4 + v;
        const int t = t0 + ql;
        float lsum = 0.f;
#pragma unroll
        for (int tn = 0; tn < 4; ++tn) {
          const int j = j0 + tn * 16 + r15;
          const bool valid = (unsigned)(t - j) <= 127u;
          const float e = valid ? __expf(sacc[tm][tn][v]) : 0.f;
          lsum += e;
          pl[ql * LSTR + tn * 16 + r15] = f2bf(e);
        }
        lf[tm * 4 + v] += lsum;
      }

    // O += P V (A from Pl, B from Vt; same-wave RAW via lgkmcnt)
#pragma unroll
    for (int kc = 0; kc < 2; ++kc) {
      bf16x8 ap[2], bv[4];
#pragma unroll
      for (int tm = 0; tm < 2; ++tm)
        ap[tm] = *(const bf16x8*)&pl[(tm * 16 + r15) * LSTR + kc * 32 + quad * 8];
#pragma unroll
      for (int tn = 0; tn < 4; ++tn)
        bv[tn] = *(const bf16x8*)&Vt[(tn * 16 + r15) * LSTR + kc * 32 + quad * 8];
#pragma unroll
      for (int tm = 0; tm < 2; ++tm)
#pragma unroll
        for (int tn = 0; tn < 4; ++tn)
          oacc[tm][tn] = __builtin_amdgcn_mfma_f32_16x16x32_bf16(ap[tm], bv[tn],
                                                                 oacc[tm][tn], 0, 0, 0);
    }
  }

  // reduce l over the 16-lane r15 group, fold sink, normalize, store bf16
#pragma unroll
  for (int i = 0; i < 8; ++i) {
    float v = lf[i];
    v += __shfl_xor(v, 1, 64);
    v += __shfl_xor(v, 2, 64);
    v += __shfl_xor(v, 4, 64);
    v += __shfl_xor(v, 8, 64);
    lf[i] = v;
  }
  const int h = kv * 4 + m;
  const float snk = __expf(sinks[h]);
#pragma unroll
  for (int tm = 0; tm < 2; ++tm)
#pragma unroll
    for (int v = 0; v < 4; ++v) {
      const float inv = 1.f / (lf[tm * 4 + v] + snk);
      const int t = t0 + tm * 16 + quad * 4 + v;
      short* op = attn_out + (size_t)(b * T_ + t) * DM + h * 64;
#pragma unroll
      for (int tn = 0; tn < 4; ++tn)
        op[tn * 16 + r15] = f2bf(oacc[tm][tn][v] * inv);
    }
}

extern "C" void kernel_launch(void* const* d_in, const int* in_sizes, int n_in,
                              void* d_out, int out_size, void* d_ws, size_t ws_size,
                              hipStream_t stream) {
  const float* x      = (const float*)d_in[0];   // fp32 (B,T,DM)
  const float* qkv_w  = (const float*)d_in[1];   // fp32 (3072,2048)
  const float* qkv_b  = (const float*)d_in[2];   // fp32 (3072,)
  const float* out_w  = (const float*)d_in[3];   // fp32 (2048,2048)
  const float* out_b  = (const float*)d_in[4];   // fp32 (2048,)
  const float* sinks  = (const float*)d_in[5];   // fp32 (32,)

  // ws layout (67.1 MB):
  //   [0, 25165824)            qkvb bf16 (4096 x 3072; v section unused)
  //   [25165824, 29360128)     vT bf16 [b][kv][64][1024]
  //   [29360128, 46137344)     x bf16, later aliased as attn bf16 out
  //   [46137344, 58720256)     qkv_w bf16
  //   [58720256, 67108864)     out_w bf16
  char* ws = (char*)d_ws;
  short* qkvb = (short*)ws;
  short* vT   = (short*)(ws + 25165824);
  short* xb   = (short*)(ws + 29360128);
  short* wqb  = (short*)(ws + 46137344);
  short* wob  = (short*)(ws + 58720256);
  short* attn = xb;                            // aliased: xb dead after gemm_qkv
  float* out  = (float*)d_out;

  cvt_kernel<<<18432, 256, 0, stream>>>(x, qkv_w, out_w, xb, wqb, wob);
  gemm_qkv<<<dim3(QKVD / 128, 4096 / 128), 256, 0, stream>>>(xb, wqb, qkv_b, qkvb, vT);
  attn_kernel<<<dim3(T_ / 32, 8, B_), 256, 0, stream>>>(qkvb, vT, sinks, attn);
  gemm_out<<<dim3(DM / 128, 4096 / 128), 256, 0, stream>>>(attn, wob, out_b, out);
}